// Round 5
// baseline (67.997 us; speedup 1.0000x reference)
//
#include <hip/hip_runtime.h>
#include <hip/hip_bf16.h>

#define LOG2E 1.4426950408889634f
#define C2    (2.0f * LOG2E)

static __device__ __forceinline__ float fast_exp2(float x) {
#if __has_builtin(__builtin_amdgcn_exp2f)
  return __builtin_amdgcn_exp2f(x);
#else
  return exp2f(x);
#endif
}
static __device__ __forceinline__ float fast_rcp(float x) {
#if __has_builtin(__builtin_amdgcn_rcpf)
  return __builtin_amdgcn_rcpf(x);
#else
  return 1.0f / x;
#endif
}

// ---------------------------------------------------------------------------
// Projections (unchanged from round 4 — ~10µs, next round's target).
// bz=0: qs[q][h] = C2 * queries@W_q (row-major)
// bz=1: ks_p[((b*64 + h/4)*256 + k)*4 + h%4] = C2 * keys@W_k (packed)
// ---------------------------------------------------------------------------
__global__ __launch_bounds__(256) void proj_kernel(
    const float* __restrict__ queries, const float* __restrict__ keys,
    const float* __restrict__ W_q,     const float* __restrict__ W_k,
    const int*   __restrict__ vlen,
    float* __restrict__ qs, float* __restrict__ ks_p)
{
  const int bz = blockIdx.z;
  const float* X = bz ? keys : queries;
  const float* W = bz ? W_k  : W_q;
  const int n0 = blockIdx.x * 64;
  const int m0 = blockIdx.y * 32;

  if (bz == 1) {                      // masked key rows: skip whole tiles
    const int vl = vlen[m0 >> 8];
    if ((m0 & 255) >= vl) return;
  }

  const int t  = threadIdx.x;
  const int tx = t & 15, ty = t >> 4;

  __shared__ __align__(16) float Xs[32 * 34];   // [d][m]
  __shared__ __align__(16) float Ws[32 * 68];   // [d][n]

  float4 acc0 = make_float4(0.f, 0.f, 0.f, 0.f);
  float4 acc1 = make_float4(0.f, 0.f, 0.f, 0.f);

  for (int kc = 0; kc < 8; ++kc) {
    {                                           // stage X 32x32 transposed
      int row = t >> 3, seg = t & 7;
      float4 v = *(const float4*)&X[(m0 + row) * 256 + kc * 32 + seg * 4];
      Xs[(seg * 4 + 0) * 34 + row] = v.x;
      Xs[(seg * 4 + 1) * 34 + row] = v.y;
      Xs[(seg * 4 + 2) * 34 + row] = v.z;
      Xs[(seg * 4 + 3) * 34 + row] = v.w;
    }
#pragma unroll
    for (int m = 0; m < 2; ++m) {               // stage W 32x64
      int idx = t + 256 * m;
      int row = idx >> 4, seg = idx & 15;
      *(float4*)&Ws[row * 68 + seg * 4] =
          *(const float4*)&W[(kc * 32 + row) * 256 + n0 + seg * 4];
    }
    __syncthreads();
#pragma unroll
    for (int kk = 0; kk < 32; ++kk) {
      float2 a  = *(const float2*)&Xs[kk * 34 + ty * 2];
      float4 bv = *(const float4*)&Ws[kk * 68 + tx * 4];
      acc0.x = fmaf(a.x, bv.x, acc0.x);
      acc0.y = fmaf(a.x, bv.y, acc0.y);
      acc0.z = fmaf(a.x, bv.z, acc0.z);
      acc0.w = fmaf(a.x, bv.w, acc0.w);
      acc1.x = fmaf(a.y, bv.x, acc1.x);
      acc1.y = fmaf(a.y, bv.y, acc1.y);
      acc1.z = fmaf(a.y, bv.z, acc1.z);
      acc1.w = fmaf(a.y, bv.w, acc1.w);
    }
    __syncthreads();
  }

  if (bz == 0) {
    float4 o0 = make_float4(acc0.x * C2, acc0.y * C2, acc0.z * C2, acc0.w * C2);
    float4 o1 = make_float4(acc1.x * C2, acc1.y * C2, acc1.z * C2, acc1.w * C2);
    *(float4*)&qs[(m0 + ty * 2 + 0) * 256 + n0 + tx * 4] = o0;
    *(float4*)&qs[(m0 + ty * 2 + 1) * 256 + n0 + tx * 4] = o1;
  } else {
    const int b  = m0 >> 8;
    const int kl = (m0 & 255) + ty * 2;
    float* base = &ks_p[((size_t)(b * 64 + (n0 >> 2) + tx) * 256 + kl) * 4];
    float4 o0 = make_float4(acc0.x * C2, acc0.y * C2, acc0.z * C2, acc0.w * C2);
    float4 o1 = make_float4(acc1.x * C2, acc1.y * C2, acc1.z * C2, acc1.w * C2);
    *(float4*)&base[0] = o0;
    *(float4*)&base[4] = o1;
  }
}

// ---------------------------------------------------------------------------
// Fused scores + softmax + PV, v3.
// Grid: 1024 blocks = B(8) x Qtiles(128), b = bx>>7 so co-resident blocks
// span 4 batches.  Block: 256 thr = 4 waves; wave w = k-group (lane owns
// k = w*64+lane), and computes TWO q-rows per kv load:
//   per h4: 1 coalesced b128 VMEM (prefetched) + 40 VALU (16 trans)
//   -> compute:VMEM ~ 11:1; q-vec + w_v are wave-uniform GLOBAL reads
//   (scalarized to SMEM), so the score loop touches no LDS at all.
// Masked k-groups skip at wave granularity.  Softmax: per-wave shuffle
// reduce + 32B LDS scalar exchange.  PV: per-wave 64-k slice, V from L2
// with depth-1 prefetch; p stored [k][2] for b64 broadcast reads.
// ---------------------------------------------------------------------------
__global__ __launch_bounds__(256, 4) void attn_kernel(
    const float* __restrict__ qs, const float* __restrict__ ks_p,
    const float* __restrict__ values, const int* __restrict__ vlen,
    const float* __restrict__ w_v, float* __restrict__ out)
{
  const int t    = threadIdx.x;
  const int lane = t & 63;
  const int w    = t >> 6;                 // k-group 0..3
  const int bx   = blockIdx.x;
  const int b    = bx >> 7;
  const int q0   = (bx & 127) * 2;

  __shared__ __align__(16) float part[4][2][256];  // 8 KB PV partials
  __shared__ __align__(16) float p2[256][2];       // 2 KB attn weights
  __shared__ float red_max[2][4];
  __shared__ float red_sum[2][4];

  const int vl = vlen[b];
  const int nj = (vl + 63) >> 6;           // active 64-wide k groups

  // Wsum = sum w_v (tanh offset term), computed per-wave
  float s0 = w_v[lane] + w_v[lane + 64] + w_v[lane + 128] + w_v[lane + 192];
#pragma unroll
  for (int off = 32; off; off >>= 1) s0 += __shfl_xor(s0, off);
  float sc0 = s0, sc1 = s0;

  const float* qp0 = qs + (size_t)(b * 256 + q0) * 256;   // wave-uniform
  const float* qp1 = qp0 + 256;

  if (w < nj) {
    const float* kp = ks_p + (size_t)b * 65536 + (w * 64 + lane) * 4;
    float4 kv  = *(const float4*)kp;
    float4 qv0 = *(const float4*)qp0;
    float4 qv1 = *(const float4*)qp1;
    float4 wv  = *(const float4*)w_v;
#pragma unroll 4
    for (int h4 = 0; h4 < 64; ++h4) {
      float4 kvn = kv, qv0n = qv0, qv1n = qv1, wvn = wv;
      if (h4 < 63) {                       // depth-1 prefetch
        kvn  = *(const float4*)(kp + (size_t)(h4 + 1) * 1024);
        qv0n = *(const float4*)(qp0 + (h4 + 1) * 4);
        qv1n = *(const float4*)(qp1 + (h4 + 1) * 4);
        wvn  = *(const float4*)(w_v + (h4 + 1) * 4);
      }
      sc0 = fmaf(-2.f * wv.x, fast_rcp(fast_exp2(qv0.x + kv.x) + 1.f), sc0);
      sc1 = fmaf(-2.f * wv.x, fast_rcp(fast_exp2(qv1.x + kv.x) + 1.f), sc1);
      sc0 = fmaf(-2.f * wv.y, fast_rcp(fast_exp2(qv0.y + kv.y) + 1.f), sc0);
      sc1 = fmaf(-2.f * wv.y, fast_rcp(fast_exp2(qv1.y + kv.y) + 1.f), sc1);
      sc0 = fmaf(-2.f * wv.z, fast_rcp(fast_exp2(qv0.z + kv.z) + 1.f), sc0);
      sc1 = fmaf(-2.f * wv.z, fast_rcp(fast_exp2(qv1.z + kv.z) + 1.f), sc1);
      sc0 = fmaf(-2.f * wv.w, fast_rcp(fast_exp2(qv0.w + kv.w) + 1.f), sc0);
      sc1 = fmaf(-2.f * wv.w, fast_rcp(fast_exp2(qv1.w + kv.w) + 1.f), sc1);
      kv = kvn; qv0 = qv0n; qv1 = qv1n; wv = wvn;
    }
  }

  // softmax across the 4 k-group waves
  const int  kglob = w * 64 + lane;
  const bool act   = (w < nj) && (kglob < vl);
  float sv0 = act ? sc0 : -1000000.0f;
  float sv1 = act ? sc1 : -1000000.0f;
  float m0 = sv0, m1 = sv1;
#pragma unroll
  for (int off = 32; off; off >>= 1) {
    m0 = fmaxf(m0, __shfl_xor(m0, off));
    m1 = fmaxf(m1, __shfl_xor(m1, off));
  }
  if (lane == 0) { red_max[0][w] = m0; red_max[1][w] = m1; }
  __syncthreads();
  const float M0 = fmaxf(fmaxf(red_max[0][0], red_max[0][1]),
                         fmaxf(red_max[0][2], red_max[0][3]));
  const float M1 = fmaxf(fmaxf(red_max[1][0], red_max[1][1]),
                         fmaxf(red_max[1][2], red_max[1][3]));
  float p0 = fast_exp2((sv0 - M0) * LOG2E);
  float p1 = fast_exp2((sv1 - M1) * LOG2E);
  p2[kglob][0] = p0;
  p2[kglob][1] = p1;
  float t0 = p0, t1 = p1;
#pragma unroll
  for (int off = 32; off; off >>= 1) {
    t0 += __shfl_xor(t0, off);
    t1 += __shfl_xor(t1, off);
  }
  if (lane == 0) { red_sum[0][w] = t0; red_sum[1][w] = t1; }
  __syncthreads();

  // PV: wave w owns k-slice [w*64, w*64+nk), d = 4*lane..+3
  if (w < nj) {
    const int kb = w * 64;
    const int nk = min(64, vl - kb);
    float4 a0 = make_float4(0.f, 0.f, 0.f, 0.f);
    float4 a1 = make_float4(0.f, 0.f, 0.f, 0.f);
    const float* Vp = values + (size_t)(b * 256 + kb) * 256 + lane * 4;
    float4 v = *(const float4*)Vp;
    for (int kk = 0; kk < nk; ++kk) {
      float4 vn = v;
      if (kk + 1 < nk) vn = *(const float4*)(Vp + (size_t)(kk + 1) * 256);
      float pk0 = p2[kb + kk][0];
      float pk1 = p2[kb + kk][1];
      a0.x = fmaf(pk0, v.x, a0.x);
      a0.y = fmaf(pk0, v.y, a0.y);
      a0.z = fmaf(pk0, v.z, a0.z);
      a0.w = fmaf(pk0, v.w, a0.w);
      a1.x = fmaf(pk1, v.x, a1.x);
      a1.y = fmaf(pk1, v.y, a1.y);
      a1.z = fmaf(pk1, v.z, a1.z);
      a1.w = fmaf(pk1, v.w, a1.w);
      v = vn;
    }
    *(float4*)&part[w][0][lane * 4] = a0;
    *(float4*)&part[w][1][lane * 4] = a1;
  }
  __syncthreads();

  // final reduce: 256 thr x 2 -> 2q x 256d outputs
#pragma unroll
  for (int rep = 0; rep < 2; ++rep) {
    int o = t + rep * 256;
    int q = o >> 8, d = o & 255;
    float s = 0.f;
    for (int ww = 0; ww < nj; ++ww) s += part[ww][q][d];
    float rsum = red_sum[q][0] + red_sum[q][1] + red_sum[q][2] + red_sum[q][3];
    out[(b * 256 + q0 + q) * 256 + d] = s * fast_rcp(rsum);
  }
}

extern "C" void kernel_launch(void* const* d_in, const int* in_sizes, int n_in,
                              void* d_out, int out_size, void* d_ws, size_t ws_size,
                              hipStream_t stream) {
  const float* queries = (const float*)d_in[0];
  const float* keys    = (const float*)d_in[1];
  const float* values  = (const float*)d_in[2];
  const int*   vlenp   = (const int*)d_in[3];
  const float* W_q     = (const float*)d_in[4];
  const float* W_k     = (const float*)d_in[5];
  const float* w_v     = (const float*)d_in[6];
  float* out = (float*)d_out;

  float* qs   = (float*)d_ws;               // 2 MiB, row-major [m][256]
  float* ks_p = qs + 2048 * 256;            // 2 MiB, packed [b][h/4][k][4]

  dim3 pgrid(4, 64, 2);
  proj_kernel<<<pgrid, 256, 0, stream>>>(queries, keys, W_q, W_k, vlenp, qs, ks_p);
  attn_kernel<<<1024, 256, 0, stream>>>(qs, ks_p, values, vlenp, w_v, out);
}

// Round 6
// 45.836 us; speedup vs baseline: 1.4835x; 1.4835x over previous
//
#include <hip/hip_runtime.h>
#include <hip/hip_bf16.h>

#define LOG2E 1.4426950408889634f
#define C2    (2.0f * LOG2E)

static __device__ __forceinline__ float fast_exp2(float x) {
#if __has_builtin(__builtin_amdgcn_exp2f)
  return __builtin_amdgcn_exp2f(x);
#else
  return exp2f(x);
#endif
}
static __device__ __forceinline__ float fast_rcp(float x) {
#if __has_builtin(__builtin_amdgcn_rcpf)
  return __builtin_amdgcn_rcpf(x);
#else
  return 1.0f / x;
#endif
}

// ---------------------------------------------------------------------------
// Projections (unchanged; ~10.7µs — next target once attn is fixed).
// bz=0: qs[q][h] = C2 * queries@W_q (row-major)
// bz=1: ks_p[((b*64 + h/4)*256 + k)*4 + h%4] = C2 * keys@W_k (packed)
// ---------------------------------------------------------------------------
__global__ __launch_bounds__(256) void proj_kernel(
    const float* __restrict__ queries, const float* __restrict__ keys,
    const float* __restrict__ W_q,     const float* __restrict__ W_k,
    const int*   __restrict__ vlen,
    float* __restrict__ qs, float* __restrict__ ks_p)
{
  const int bz = blockIdx.z;
  const float* X = bz ? keys : queries;
  const float* W = bz ? W_k  : W_q;
  const int n0 = blockIdx.x * 64;
  const int m0 = blockIdx.y * 32;

  if (bz == 1) {                      // masked key rows: skip whole tiles
    const int vl = vlen[m0 >> 8];
    if ((m0 & 255) >= vl) return;
  }

  const int t  = threadIdx.x;
  const int tx = t & 15, ty = t >> 4;

  __shared__ __align__(16) float Xs[32 * 34];   // [d][m]
  __shared__ __align__(16) float Ws[32 * 68];   // [d][n]

  float4 acc0 = make_float4(0.f, 0.f, 0.f, 0.f);
  float4 acc1 = make_float4(0.f, 0.f, 0.f, 0.f);

  for (int kc = 0; kc < 8; ++kc) {
    {                                           // stage X 32x32 transposed
      int row = t >> 3, seg = t & 7;
      float4 v = *(const float4*)&X[(m0 + row) * 256 + kc * 32 + seg * 4];
      Xs[(seg * 4 + 0) * 34 + row] = v.x;
      Xs[(seg * 4 + 1) * 34 + row] = v.y;
      Xs[(seg * 4 + 2) * 34 + row] = v.z;
      Xs[(seg * 4 + 3) * 34 + row] = v.w;
    }
#pragma unroll
    for (int m = 0; m < 2; ++m) {               // stage W 32x64
      int idx = t + 256 * m;
      int row = idx >> 4, seg = idx & 15;
      *(float4*)&Ws[row * 68 + seg * 4] =
          *(const float4*)&W[(kc * 32 + row) * 256 + n0 + seg * 4];
    }
    __syncthreads();
#pragma unroll
    for (int kk = 0; kk < 32; ++kk) {
      float2 a  = *(const float2*)&Xs[kk * 34 + ty * 2];
      float4 bv = *(const float4*)&Ws[kk * 68 + tx * 4];
      acc0.x = fmaf(a.x, bv.x, acc0.x);
      acc0.y = fmaf(a.x, bv.y, acc0.y);
      acc0.z = fmaf(a.x, bv.z, acc0.z);
      acc0.w = fmaf(a.x, bv.w, acc0.w);
      acc1.x = fmaf(a.y, bv.x, acc1.x);
      acc1.y = fmaf(a.y, bv.y, acc1.y);
      acc1.z = fmaf(a.y, bv.z, acc1.z);
      acc1.w = fmaf(a.y, bv.w, acc1.w);
    }
    __syncthreads();
  }

  if (bz == 0) {
    float4 o0 = make_float4(acc0.x * C2, acc0.y * C2, acc0.z * C2, acc0.w * C2);
    float4 o1 = make_float4(acc1.x * C2, acc1.y * C2, acc1.z * C2, acc1.w * C2);
    *(float4*)&qs[(m0 + ty * 2 + 0) * 256 + n0 + tx * 4] = o0;
    *(float4*)&qs[(m0 + ty * 2 + 1) * 256 + n0 + tx * 4] = o1;
  } else {
    const int b  = m0 >> 8;
    const int kl = (m0 & 255) + ty * 2;
    float* base = &ks_p[((size_t)(b * 64 + (n0 >> 2) + tx) * 256 + kl) * 4];
    float4 o0 = make_float4(acc0.x * C2, acc0.y * C2, acc0.z * C2, acc0.w * C2);
    float4 o1 = make_float4(acc1.x * C2, acc1.y * C2, acc1.z * C2, acc1.w * C2);
    *(float4*)&base[0] = o0;
    *(float4*)&base[4] = o1;
  }
}

// ---------------------------------------------------------------------------
// Score inner loop, NJ = active 64-wide k-groups (compile-time).
// Wave = h-quarter: h4 in [h4b, h4b+16).  Per iter: NJ coalesced b128
// k-loads (all independent -> NJ in flight) + wave-uniform q/w s_loads +
// 16*NJ trans.  Accumulates sc[j][q] = sum_h wv_h * rcp(1+exp2(q_h+k_h)).
// ---------------------------------------------------------------------------
template <int NJ>
__device__ __forceinline__ void score_loop(
    const float* __restrict__ kp,    // ks_p + b*65536 + lane*4
    const float* __restrict__ qp0, const float* __restrict__ qp1,
    const float* __restrict__ wvp, int h4b, float (&sc)[4][2])
{
  if constexpr (NJ <= 2) {           // depth-1 prefetch (reg headroom)
    float4 kv[NJ], kvn[NJ];
#pragma unroll
    for (int j = 0; j < NJ; ++j)
      kv[j] = *(const float4*)(kp + h4b * 1024 + j * 256);
#pragma unroll 2
    for (int h4 = h4b; h4 < h4b + 16; ++h4) {
      const int h4n = (h4 + 1 < h4b + 16) ? h4 + 1 : h4;
#pragma unroll
      for (int j = 0; j < NJ; ++j)
        kvn[j] = *(const float4*)(kp + h4n * 1024 + j * 256);
      float4 qv0 = *(const float4*)(qp0 + h4 * 4);
      float4 qv1 = *(const float4*)(qp1 + h4 * 4);
      float4 wv  = *(const float4*)(wvp + h4 * 4);
#pragma unroll
      for (int j = 0; j < NJ; ++j) {
        sc[j][0] = fmaf(wv.x, fast_rcp(fast_exp2(qv0.x + kv[j].x) + 1.f), sc[j][0]);
        sc[j][1] = fmaf(wv.x, fast_rcp(fast_exp2(qv1.x + kv[j].x) + 1.f), sc[j][1]);
        sc[j][0] = fmaf(wv.y, fast_rcp(fast_exp2(qv0.y + kv[j].y) + 1.f), sc[j][0]);
        sc[j][1] = fmaf(wv.y, fast_rcp(fast_exp2(qv1.y + kv[j].y) + 1.f), sc[j][1]);
        sc[j][0] = fmaf(wv.z, fast_rcp(fast_exp2(qv0.z + kv[j].z) + 1.f), sc[j][0]);
        sc[j][1] = fmaf(wv.z, fast_rcp(fast_exp2(qv1.z + kv[j].z) + 1.f), sc[j][1]);
        sc[j][0] = fmaf(wv.w, fast_rcp(fast_exp2(qv0.w + kv[j].w) + 1.f), sc[j][0]);
        sc[j][1] = fmaf(wv.w, fast_rcp(fast_exp2(qv1.w + kv[j].w) + 1.f), sc[j][1]);
      }
#pragma unroll
      for (int j = 0; j < NJ; ++j) kv[j] = kvn[j];
    }
  } else {                           // NJ>=3: NJ loads/iter already in flight
#pragma unroll 2
    for (int h4 = h4b; h4 < h4b + 16; ++h4) {
      float4 kv[NJ];
#pragma unroll
      for (int j = 0; j < NJ; ++j)
        kv[j] = *(const float4*)(kp + h4 * 1024 + j * 256);
      float4 qv0 = *(const float4*)(qp0 + h4 * 4);
      float4 qv1 = *(const float4*)(qp1 + h4 * 4);
      float4 wv  = *(const float4*)(wvp + h4 * 4);
#pragma unroll
      for (int j = 0; j < NJ; ++j) {
        sc[j][0] = fmaf(wv.x, fast_rcp(fast_exp2(qv0.x + kv[j].x) + 1.f), sc[j][0]);
        sc[j][1] = fmaf(wv.x, fast_rcp(fast_exp2(qv1.x + kv[j].x) + 1.f), sc[j][1]);
        sc[j][0] = fmaf(wv.y, fast_rcp(fast_exp2(qv0.y + kv[j].y) + 1.f), sc[j][0]);
        sc[j][1] = fmaf(wv.y, fast_rcp(fast_exp2(qv1.y + kv[j].y) + 1.f), sc[j][1]);
        sc[j][0] = fmaf(wv.z, fast_rcp(fast_exp2(qv0.z + kv[j].z) + 1.f), sc[j][0]);
        sc[j][1] = fmaf(wv.z, fast_rcp(fast_exp2(qv1.z + kv[j].z) + 1.f), sc[j][1]);
        sc[j][0] = fmaf(wv.w, fast_rcp(fast_exp2(qv0.w + kv[j].w) + 1.f), sc[j][0]);
        sc[j][1] = fmaf(wv.w, fast_rcp(fast_exp2(qv1.w + kv[j].w) + 1.f), sc[j][1]);
      }
    }
  }
}

// ---------------------------------------------------------------------------
// Fused scores + softmax + PV, v4.
// Grid: 1024 blocks; b = ((bx&7)+(bx>>8))&7 (bijective per q-tile) so the
// 4 co-resident blocks on a CU span 4 batches.  Block: 256 thr = 4 waves;
// wave hq = h-QUARTER (not k-group): every wave runs nj*16 identical
// iterations regardless of vl -> zero idle waves.  Partial scores exchanged
// via 8 KB LDS (reused for PV partials).  score = Wsum - 2*sum(wv*rcp(..)).
// PV: parity-4 k-split (balanced for all vl), V coalesced b128 from L2.
// ---------------------------------------------------------------------------
__global__ __launch_bounds__(256, 4) void attn_kernel(
    const float* __restrict__ qs, const float* __restrict__ ks_p,
    const float* __restrict__ values, const int* __restrict__ vlen,
    const float* __restrict__ w_v, float* __restrict__ out)
{
  const int t    = threadIdx.x;
  const int lane = t & 63;
  const int hq   = t >> 6;                 // h-quarter 0..3
  const int bx   = blockIdx.x;
  const int b    = ((bx & 7) + (bx >> 8)) & 7;
  const int q0   = (bx >> 3) * 2;

  __shared__ __align__(16) float sbuf[2048];   // sc parts, then PV parts
  __shared__ __align__(8)  float p2[512];      // [k][2 q]
  __shared__ float rsum_lds[2];

  const int vl = vlen[b];
  const int nj = (vl + 63) >> 6;

  // Wsum = sum(w_v)
  float s0 = w_v[lane] + w_v[lane + 64] + w_v[lane + 128] + w_v[lane + 192];
#pragma unroll
  for (int off = 32; off; off >>= 1) s0 += __shfl_xor(s0, off);
  const float Wsum = s0;

  const float* qp0 = qs + (size_t)(b * 256 + q0) * 256;  // wave-uniform
  const float* qp1 = qp0 + 256;
  const float* kp  = ks_p + (size_t)b * 65536 + lane * 4;
  const int h4b = hq * 16;

  float sc[4][2] = {};
  switch (nj) {
    case 1:  score_loop<1>(kp, qp0, qp1, w_v, h4b, sc); break;
    case 2:  score_loop<2>(kp, qp0, qp1, w_v, h4b, sc); break;
    case 3:  score_loop<3>(kp, qp0, qp1, w_v, h4b, sc); break;
    default: score_loop<4>(kp, qp0, qp1, w_v, h4b, sc); break;
  }

  // write h-quarter partials: sbuf[((hq*4 + j)*64 + lane)*2 + q]
#pragma unroll
  for (int j = 0; j < 4; ++j)
    *(float2*)&sbuf[((hq * 4 + j) * 64 + lane) * 2] =
        make_float2(sc[j][0], sc[j][1]);
  __syncthreads();

  // softmax: waves 0,1 each own one q-row
  if (hq < 2) {
    const int q = hq;
    float scores[4];
    float mx = -3.4e38f;
#pragma unroll 4
    for (int j = 0; j < nj; ++j) {
      float s = sbuf[((0 * 4 + j) * 64 + lane) * 2 + q] +
                sbuf[((1 * 4 + j) * 64 + lane) * 2 + q] +
                sbuf[((2 * 4 + j) * 64 + lane) * 2 + q] +
                sbuf[((3 * 4 + j) * 64 + lane) * 2 + q];
      float v = Wsum - 2.f * s;
      if (j * 64 + lane >= vl) v = -1000000.0f;
      scores[j] = v;
      mx = fmaxf(mx, v);
    }
#pragma unroll
    for (int off = 32; off; off >>= 1) mx = fmaxf(mx, __shfl_xor(mx, off));
    float sum = 0.f;
#pragma unroll 4
    for (int j = 0; j < nj; ++j) {
      float p = fast_exp2((scores[j] - mx) * LOG2E);
      p2[(j * 64 + lane) * 2 + q] = p;
      sum += p;
    }
#pragma unroll
    for (int off = 32; off; off >>= 1) sum += __shfl_xor(sum, off);
    if (lane == 0) rsum_lds[q] = sum;
  }
  __syncthreads();

  // PV: wave hq takes k = hq (mod 4); every wave ~vl/4 rows for any vl
  float4 a0 = make_float4(0.f, 0.f, 0.f, 0.f);
  float4 a1 = make_float4(0.f, 0.f, 0.f, 0.f);
  const float* Vb = values + (size_t)b * 65536 + lane * 4;
#pragma unroll 2
  for (int k = hq; k < vl; k += 4) {
    float2 pk = *(const float2*)&p2[k * 2];            // LDS broadcast
    float4 v  = *(const float4*)(Vb + (size_t)k * 256);
    a0.x = fmaf(pk.x, v.x, a0.x);
    a0.y = fmaf(pk.x, v.y, a0.y);
    a0.z = fmaf(pk.x, v.z, a0.z);
    a0.w = fmaf(pk.x, v.w, a0.w);
    a1.x = fmaf(pk.y, v.x, a1.x);
    a1.y = fmaf(pk.y, v.y, a1.y);
    a1.z = fmaf(pk.y, v.z, a1.z);
    a1.w = fmaf(pk.y, v.w, a1.w);
  }
  // PV partials reuse sbuf: [hq][q][256]
  *(float4*)&sbuf[(hq * 2 + 0) * 256 + lane * 4] = a0;
  *(float4*)&sbuf[(hq * 2 + 1) * 256 + lane * 4] = a1;
  __syncthreads();

  // final reduce: 256 thr x 2 -> 2q x 256d
#pragma unroll
  for (int rep = 0; rep < 2; ++rep) {
    int o = t + rep * 256;
    int q = o >> 8, d = o & 255;
    float s = sbuf[(0 + q) * 256 + d] + sbuf[(2 + q) * 256 + d] +
              sbuf[(4 + q) * 256 + d] + sbuf[(6 + q) * 256 + d];
    out[(b * 256 + q0 + q) * 256 + d] = s * fast_rcp(rsum_lds[q]);
  }
}

extern "C" void kernel_launch(void* const* d_in, const int* in_sizes, int n_in,
                              void* d_out, int out_size, void* d_ws, size_t ws_size,
                              hipStream_t stream) {
  const float* queries = (const float*)d_in[0];
  const float* keys    = (const float*)d_in[1];
  const float* values  = (const float*)d_in[2];
  const int*   vlenp   = (const int*)d_in[3];
  const float* W_q     = (const float*)d_in[4];
  const float* W_k     = (const float*)d_in[5];
  const float* w_v     = (const float*)d_in[6];
  float* out = (float*)d_out;

  float* qs   = (float*)d_ws;               // 2 MiB, row-major [m][256]
  float* ks_p = qs + 2048 * 256;            // 2 MiB, packed [b][h/4][k][4]

  dim3 pgrid(4, 64, 2);
  proj_kernel<<<pgrid, 256, 0, stream>>>(queries, keys, W_q, W_k, vlenp, qs, ks_p);
  attn_kernel<<<1024, 256, 0, stream>>>(qs, ks_p, values, vlenp, w_v, out);
}